// Round 1
// baseline (237.107 us; speedup 1.0000x reference)
//
#include <hip/hip_runtime.h>
#include <cstdint>
#include <cstddef>

#define G_ 8
#define T_ 2048
#define H_ 512
#define E_ 8
#define F_ 2048
#define C_ 256

typedef __bf16 bf16x8 __attribute__((ext_vector_type(8)));
typedef float f32x4 __attribute__((ext_vector_type(4)));

__device__ __forceinline__ unsigned short f2bf(float f) {
  unsigned u = __float_as_uint(f);
  u += 0x7FFFu + ((u >> 16) & 1u);
  return (unsigned short)(u >> 16);
}

__device__ __forceinline__ void gload_lds16(const void* g, void* l) {
  __builtin_amdgcn_global_load_lds(
      (const __attribute__((address_space(1))) void*)g,
      (__attribute__((address_space(3))) void*)l, 16, 0, 0);
}

// ---------------- transpose + fp32->bf16 convert ----------------
// in: [B][R][Cc] fp32   out: [B][Cc][R] bf16
__global__ void transconv_kernel(const float* __restrict__ in,
                                 unsigned short* __restrict__ out,
                                 int R, int Cc, int tC) {
  __shared__ float tile[32][33];
  int tid = threadIdx.x, tx = tid & 31, ty = tid >> 5;
  int nTilesPerB = (R / 32) * tC;
  int b = blockIdx.x / nTilesPerB;
  int rem = blockIdx.x % nTilesPerB;
  int tr = rem / tC, tc = rem % tC;
  const float* ib = in + (size_t)b * R * Cc;
  unsigned short* ob = out + (size_t)b * R * Cc;
#pragma unroll
  for (int i = 0; i < 4; ++i)
    tile[ty + i * 8][tx] = ib[(size_t)(tr * 32 + ty + i * 8) * Cc + tc * 32 + tx];
  __syncthreads();
#pragma unroll
  for (int i = 0; i < 4; ++i)
    ob[(size_t)(tc * 32 + ty + i * 8) * R + tr * 32 + tx] = f2bf(tile[tx][ty + i * 8]);
}

// ---------------- router: probs_et [G][E][T] fp32 ----------------
__global__ void router_kernel(const float* __restrict__ x, const float* __restrict__ rk,
                              const float* __restrict__ rb, float* __restrict__ probs) {
  __shared__ float rks[H_ * E_];  // 16KB
  int tid = threadIdx.x;
  for (int i = tid; i < H_ * E_ / 4; i += 256)
    ((float4*)rks)[i] = ((const float4*)rk)[i];
  __syncthreads();
  int wid = tid >> 6, lane = tid & 63;
  int row = blockIdx.x * 4 + wid;  // g*T + t
  float acc[E_];
#pragma unroll
  for (int e = 0; e < E_; ++e) acc[e] = 0.f;
  const float* xr = x + (size_t)row * H_;
#pragma unroll
  for (int j = 0; j < H_ / 64; ++j) {
    int h = j * 64 + lane;
    float xv = xr[h];
    const float4* r4 = (const float4*)&rks[h * E_];
    float4 r0 = r4[0], r1 = r4[1];
    acc[0] += xv * r0.x; acc[1] += xv * r0.y; acc[2] += xv * r0.z; acc[3] += xv * r0.w;
    acc[4] += xv * r1.x; acc[5] += xv * r1.y; acc[6] += xv * r1.z; acc[7] += xv * r1.w;
  }
#pragma unroll
  for (int e = 0; e < E_; ++e) {
#pragma unroll
    for (int off = 32; off > 0; off >>= 1) acc[e] += __shfl_xor(acc[e], off);
  }
  float l[E_];
  float mx = -1e30f;
#pragma unroll
  for (int e = 0; e < E_; ++e) { l[e] = acc[e] + rb[e]; mx = fmaxf(mx, l[e]); }
  float s = 0.f;
#pragma unroll
  for (int e = 0; e < E_; ++e) { l[e] = expf(l[e] - mx); s += l[e]; }
  float inv = 1.0f / s;
  int g = row >> 11, t = row & (T_ - 1);
  if (lane < E_) probs[((size_t)(g * E_ + lane)) * T_ + t] = l[lane] * inv;
}

// ---------------- top-k (k=256) per (g,e) via bitonic sort ----------------
__global__ void topk_kernel(const float* __restrict__ probs, int* __restrict__ idx,
                            float* __restrict__ gate) {
  __shared__ unsigned long long keys[T_];  // 16KB
  int ge = blockIdx.x, tid = threadIdx.x;
  const float* p = probs + (size_t)ge * T_;
  for (int t = tid; t < T_; t += 256) {
    unsigned pb = __float_as_uint(p[t]);  // softmax output > 0 -> bits monotonic
    keys[t] = ((unsigned long long)pb << 32) | (unsigned)(~t);  // tie: lower t wins
  }
  __syncthreads();
  for (unsigned k = 2; k <= T_; k <<= 1) {
    for (unsigned j = k >> 1; j > 0; j >>= 1) {
      for (unsigned w = tid; w < T_ / 2; w += 256) {
        unsigned i = ((w & ~(j - 1)) << 1) | (w & (j - 1));
        unsigned q = i + j;
        unsigned long long a = keys[i], b = keys[q];
        bool sw = ((i & k) == 0) ? (a < b) : (a > b);  // descending sort
        if (sw) { keys[i] = b; keys[q] = a; }
      }
      __syncthreads();
    }
  }
  if (tid < C_) {
    unsigned long long kk = keys[tid];
    gate[ge * C_ + tid] = __uint_as_float((unsigned)(kk >> 32));
    idx[ge * C_ + tid] = (int)(~(unsigned)kk);
  }
}

// ---------------- gather: xin[ge][c][h] bf16 = x[g][idx][h] ----------------
__global__ void gather_kernel(const float* __restrict__ x, const int* __restrict__ idx,
                              unsigned short* __restrict__ xin) {
  int tid = threadIdx.x, wid = tid >> 6, lane = tid & 63;
  int r = blockIdx.x * 4 + wid;  // ge*C + c
  int ge = r >> 8;
  int g = ge >> 3;
  int t = idx[r];
  const float* src = x + ((size_t)(g * T_ + t)) * H_;
  unsigned short* dst = xin + (size_t)r * H_;
#pragma unroll
  for (int j = 0; j < 2; ++j) {
    int h = j * 256 + lane * 4;
    float4 v = *(const float4*)&src[h];
    ushort4 o;
    o.x = f2bf(v.x); o.y = f2bf(v.y); o.z = f2bf(v.z); o.w = f2bf(v.w);
    *(ushort4*)&dst[h] = o;
  }
}

// ---------------- GEMM1: hmid = gelu(xin @ wi + bi), bf16 out ----------------
// A: xin [ge][256][512] bf16 row-major; Bt: wiT [e][F][H] bf16 (row n=f, K=H contiguous)
__global__ __launch_bounds__(256) void gemm1_kernel(const unsigned short* __restrict__ xin,
                                                    const unsigned short* __restrict__ wiT,
                                                    const float* __restrict__ bi,
                                                    unsigned short* __restrict__ hmid) {
  __shared__ unsigned short As[128 * 64];
  __shared__ unsigned short Bs[128 * 64];
  int bid = blockIdx.x;
  int ge = bid >> 5;              // 2*16 = 32 tiles per (g,e)
  int tile = bid & 31;
  int tm = tile >> 4, tn = tile & 15;
  int e = ge & 7;
  int tid = threadIdx.x, wid = tid >> 6, lane = tid & 63;
  const unsigned short* Abase = xin + (size_t)ge * C_ * H_ + (size_t)tm * 128 * H_;
  const unsigned short* Bbase = wiT + (size_t)e * F_ * H_ + (size_t)tn * 128 * H_;
  f32x4 acc[4][4] = {};
  int wm = wid >> 1, wn = wid & 1;
  int srow = lane >> 3, scol = (lane & 7) * 8;
  for (int kt = 0; kt < H_ / 64; ++kt) {
#pragma unroll
    for (int q = 0; q < 4; ++q) {
      int ch = wid + 4 * q;  // 16 chunks of 1KB each per buffer
      gload_lds16(Abase + (size_t)(ch * 8 + srow) * H_ + kt * 64 + scol, &As[ch * 512]);
      gload_lds16(Bbase + (size_t)(ch * 8 + srow) * H_ + kt * 64 + scol, &Bs[ch * 512]);
    }
    __syncthreads();  // drains vmcnt -> staging complete
#pragma unroll
    for (int kk = 0; kk < 2; ++kk) {
      bf16x8 af[4], bfr[4];
#pragma unroll
      for (int m = 0; m < 4; ++m)
        af[m] = *(const bf16x8*)&As[(wm * 64 + m * 16 + (lane & 15)) * 64 + kk * 32 + (lane >> 4) * 8];
#pragma unroll
      for (int n = 0; n < 4; ++n)
        bfr[n] = *(const bf16x8*)&Bs[(wn * 64 + n * 16 + (lane & 15)) * 64 + kk * 32 + (lane >> 4) * 8];
#pragma unroll
      for (int m = 0; m < 4; ++m)
#pragma unroll
        for (int n = 0; n < 4; ++n)
          acc[m][n] = __builtin_amdgcn_mfma_f32_16x16x32_bf16(af[m], bfr[n], acc[m][n], 0, 0, 0);
    }
    __syncthreads();
  }
  unsigned short* Cb = hmid + (size_t)ge * C_ * F_;
  int row0 = tm * 128 + wm * 64;
  int col0 = tn * 128 + wn * 64;
#pragma unroll
  for (int m = 0; m < 4; ++m) {
#pragma unroll
    for (int n = 0; n < 4; ++n) {
      int col = col0 + n * 16 + (lane & 15);
      float bv = bi[e * F_ + col];
#pragma unroll
      for (int r = 0; r < 4; ++r) {
        int row = row0 + m * 16 + (lane >> 4) * 4 + r;
        float v = acc[m][n][r] + bv;
        float gl = 0.5f * v * (1.0f + erff(v * 0.70710678118f));  // exact gelu
        Cb[(size_t)row * F_ + col] = f2bf(gl);
      }
    }
  }
}

// ---------------- GEMM2: y[g][t][:] += gate * (hmid @ wo + bo) ----------------
// A: hmid [ge][256][2048] bf16; Bt: woT [e][H][F] bf16 (row n=h, K=F contiguous)
__global__ __launch_bounds__(256) void gemm2_kernel(const unsigned short* __restrict__ hmid,
                                                    const unsigned short* __restrict__ woT,
                                                    const float* __restrict__ bo,
                                                    const int* __restrict__ idx,
                                                    const float* __restrict__ gate,
                                                    float* __restrict__ y) {
  __shared__ unsigned short As[128 * 64];
  __shared__ unsigned short Bs[128 * 64];
  int bid = blockIdx.x;
  int ge = bid >> 3;              // 2*4 = 8 tiles per (g,e)
  int tile = bid & 7;
  int tm = tile >> 2, tn = tile & 3;
  int e = ge & 7, g = ge >> 3;
  int tid = threadIdx.x, wid = tid >> 6, lane = tid & 63;
  const unsigned short* Abase = hmid + (size_t)ge * C_ * F_ + (size_t)tm * 128 * F_;
  const unsigned short* Bbase = woT + (size_t)e * H_ * F_ + (size_t)tn * 128 * F_;
  f32x4 acc[4][4] = {};
  int wm = wid >> 1, wn = wid & 1;
  int srow = lane >> 3, scol = (lane & 7) * 8;
  for (int kt = 0; kt < F_ / 64; ++kt) {
#pragma unroll
    for (int q = 0; q < 4; ++q) {
      int ch = wid + 4 * q;
      gload_lds16(Abase + (size_t)(ch * 8 + srow) * F_ + kt * 64 + scol, &As[ch * 512]);
      gload_lds16(Bbase + (size_t)(ch * 8 + srow) * F_ + kt * 64 + scol, &Bs[ch * 512]);
    }
    __syncthreads();
#pragma unroll
    for (int kk = 0; kk < 2; ++kk) {
      bf16x8 af[4], bfr[4];
#pragma unroll
      for (int m = 0; m < 4; ++m)
        af[m] = *(const bf16x8*)&As[(wm * 64 + m * 16 + (lane & 15)) * 64 + kk * 32 + (lane >> 4) * 8];
#pragma unroll
      for (int n = 0; n < 4; ++n)
        bfr[n] = *(const bf16x8*)&Bs[(wn * 64 + n * 16 + (lane & 15)) * 64 + kk * 32 + (lane >> 4) * 8];
#pragma unroll
      for (int m = 0; m < 4; ++m)
#pragma unroll
        for (int n = 0; n < 4; ++n)
          acc[m][n] = __builtin_amdgcn_mfma_f32_16x16x32_bf16(af[m], bfr[n], acc[m][n], 0, 0, 0);
    }
    __syncthreads();
  }
  const int* idxg = idx + ge * C_;
  const float* gateg = gate + ge * C_;
  float* yb = y + (size_t)g * T_ * H_;
  int row0 = tm * 128 + wm * 64;
  int col0 = tn * 128 + wn * 64;
#pragma unroll
  for (int m = 0; m < 4; ++m) {
#pragma unroll
    for (int r = 0; r < 4; ++r) {
      int row = row0 + m * 16 + (lane >> 4) * 4 + r;
      int t = idxg[row];
      float gt = gateg[row];
      float* yrow = yb + (size_t)t * H_;
#pragma unroll
      for (int n = 0; n < 4; ++n) {
        int col = col0 + n * 16 + (lane & 15);
        float v = acc[m][n][r] + bo[e * H_ + col];
        atomicAdd(&yrow[col], gt * v);
      }
    }
  }
}

extern "C" void kernel_launch(void* const* d_in, const int* in_sizes, int n_in,
                              void* d_out, int out_size, void* d_ws, size_t ws_size,
                              hipStream_t stream) {
  const float* x  = (const float*)d_in[0];
  const float* rk = (const float*)d_in[1];
  const float* rb = (const float*)d_in[2];
  const float* wi = (const float*)d_in[3];
  const float* bi = (const float*)d_in[4];
  const float* wo = (const float*)d_in[5];
  const float* bo = (const float*)d_in[6];
  float* y = (float*)d_out;

  // workspace layout (bytes)
  const size_t WI_T = 0;                       // 16 MB bf16 [E][F][H]
  const size_t WO_T = 16777216;                // 16 MB bf16 [E][H][F]
  const size_t PROB = 33554432;                // 512 KB fp32 [G][E][T]
  const size_t IDXO = 34078720;                // 64 KB int32 [G][E][C]
  const size_t GATO = 34144256;                // 64 KB fp32
  const size_t XINO = 34209792;                // 16 MB bf16 [G][E][C][H]
  const size_t HMID = 50987008;                // 64 MB bf16 [G][E][C][F]
  const size_t NEED = 118095872;
  if (ws_size < NEED) return;  // insufficient scratch -> clean fail (y stays 0)

  char* ws = (char*)d_ws;
  unsigned short* wiT = (unsigned short*)(ws + WI_T);
  unsigned short* woT = (unsigned short*)(ws + WO_T);
  float* probs = (float*)(ws + PROB);
  int* idx = (int*)(ws + IDXO);
  float* gate = (float*)(ws + GATO);
  unsigned short* xin = (unsigned short*)(ws + XINO);
  unsigned short* hmid = (unsigned short*)(ws + HMID);

  hipMemsetAsync(d_out, 0, (size_t)out_size * sizeof(float), stream);

  // wi [E][H][F] -> wiT [E][F][H];  wo [E][F][H] -> woT [E][H][F]
  transconv_kernel<<<E_ * (H_ / 32) * (F_ / 32), 256, 0, stream>>>(wi, wiT, H_, F_, F_ / 32);
  transconv_kernel<<<E_ * (F_ / 32) * (H_ / 32), 256, 0, stream>>>(wo, woT, F_, H_, H_ / 32);
  router_kernel<<<G_ * T_ / 4, 256, 0, stream>>>(x, rk, rb, probs);
  topk_kernel<<<G_ * E_, 256, 0, stream>>>(probs, idx, gate);
  gather_kernel<<<G_ * E_ * C_ / 4, 256, 0, stream>>>(x, idx, xin);
  gemm1_kernel<<<G_ * E_ * 32, 256, 0, stream>>>(xin, wiT, bi, hmid);
  gemm2_kernel<<<G_ * E_ * 8, 256, 0, stream>>>(hmid, woT, bo, idx, gate, y);
}